// Round 11
// baseline (232.724 us; speedup 1.0000x reference)
//
#include <hip/hip_runtime.h>

// ---------------------------------------------------------------------------
// 2-layer GCN + global mean pool, MI355X (gfx950).
//   A_hat = D^{-1/2}(A+I)D^{-1/2}
//   G' = dinv*(X @ W1) fp16 [MFMA];  H'' = dinv*relu(dinv*A_sum(G')+b1) fp16
//   out = pool(dinv*A_sum(H'')) @ W2 + b2
// R11: agg kernels restructured to a FLAT SEGMENTED EDGE STREAM: CSR segments
// carry deg+1 entries (self-edge first), waves run one continuous unroll-8
// gather loop across node boundaries (uniform flush on e>=rowstart[i+1]).
// Removes the per-node MLP collapse (self-term dependent load + short loops).
// ---------------------------------------------------------------------------

#define D 128
#define NGRAPH 64
#define SCAN_B 1024
#define AGG_BLOCKS 2048   // 8192 waves = 32/CU

typedef _Float16 h16x2 __attribute__((ext_vector_type(2)));
typedef _Float16 f16x8 __attribute__((ext_vector_type(8)));
typedef float    f32x4 __attribute__((ext_vector_type(4)));

__device__ __forceinline__ float2 h2f(unsigned u) {
    h16x2 h = __builtin_bit_cast(h16x2, u);
    return make_float2((float)h.x, (float)h.y);
}
__device__ __forceinline__ unsigned f2h(float x, float y) {
    h16x2 h;
    h.x = (_Float16)x;
    h.y = (_Float16)y;
    return __builtin_bit_cast(unsigned, h);
}

// --- diagnostic: all-zero output (ws too small) ----------------------------
__global__ void zero_out_kernel(float* __restrict__ out, int n) {
    int i = blockIdx.x * blockDim.x + threadIdx.x;
    if (i < n) out[i] = 0.f;
}

// --- Fused: X->fp16 conversion | W1->fp16 MFMA-B pack | degree count -------
__global__ __launch_bounds__(256) void conv_count_kernel(const float* __restrict__ X,
                                                         _Float16* __restrict__ Xh,
                                                         const float* __restrict__ W1,
                                                         _Float16* __restrict__ WB,
                                                         const int* __restrict__ ei,
                                                         int* __restrict__ deg,
                                                         int N, int E, int cb) {
    int b = (int)blockIdx.x;
    if (b < cb) {
        int idx = b * 256 + (int)threadIdx.x;     // float4 index
        int total = N * (D / 4);
        if (idx < total) {
            float4 v = ((const float4*)X)[idx];
            uint2 o;
            o.x = f2h(v.x, v.y);
            o.y = f2h(v.z, v.w);
            ((uint2*)Xh)[idx] = o;
        }
        return;
    }
    if (b < cb + 8) {
        // WB[((kt*8+nt)*64+lane)*8+j] = W1[(kt*32+(lane>>4)*8+j)*D + nt*16+(lane&15)]
        int idx = (b - cb) * 256 + (int)threadIdx.x;   // 0..2047
        int lane = idx & 63;
        int nt   = (idx >> 6) & 7;
        int kt   = idx >> 9;
        int col  = nt * 16 + (lane & 15);
        int krow = kt * 32 + (lane >> 4) * 8;
#pragma unroll
        for (int j = 0; j < 8; ++j)
            WB[idx * 8 + j] = (_Float16)W1[(krow + j) * D + col];
        return;
    }
    int e = (b - cb - 8) * 256 + (int)threadIdx.x;
    if (e < E) {
        int d = ei[E + e];
        if (d >= 0 && d < N) atomicAdd(&deg[d], 1);
    }
}

// per-block scan of (deg+1) -> local exclusive prefix; also emits dinv.
__global__ __launch_bounds__(SCAN_B) void block_scan_kernel(const int* __restrict__ deg,
                                                            int* __restrict__ rowstart,
                                                            int* __restrict__ bsum,
                                                            float* __restrict__ dinv,
                                                            int N) {
    __shared__ int sc[SCAN_B];
    int t = threadIdx.x;
    int i = blockIdx.x * SCAN_B + t;
    int d0 = (i < N) ? deg[i] : 0;
    int orig = (i < N) ? (d0 + 1) : 0;            // +1 self-edge slot
    int v = orig;
    sc[t] = v;
    __syncthreads();
    for (int off = 1; off < SCAN_B; off <<= 1) {
        int add = (t >= off) ? sc[t - off] : 0;
        __syncthreads();
        v += add;
        sc[t] = v;
        __syncthreads();
    }
    if (i < N) {
        rowstart[i] = v - orig;                      // local exclusive
        dinv[i]     = rsqrtf((float)d0 + 1.0f);      // +1 self loop
    }
    if (t == SCAN_B - 1) bsum[blockIdx.x] = v;
}

// add block offsets; place self-edge at segment head; cursor = head+1.
__global__ __launch_bounds__(SCAN_B) void finalize_scan_kernel(const int* __restrict__ bsum,
                                                               int* __restrict__ rowstart,
                                                               int* __restrict__ cursor,
                                                               int* __restrict__ colidx,
                                                               int N, int nblk, int EN) {
    __shared__ int s_off;
    if (threadIdx.x < 64) {
        int lane = (int)threadIdx.x;
        int v = (lane < nblk && lane < (int)blockIdx.x) ? bsum[lane] : 0;
        for (int off = 32; off > 0; off >>= 1) v += __shfl_down(v, off);
        if (lane == 0) s_off = v;
    }
    __syncthreads();
    int i = blockIdx.x * SCAN_B + threadIdx.x;
    if (i < N) {
        int rs = rowstart[i] + s_off;
        rowstart[i] = rs;
        cursor[i]   = rs + 1;      // slot 0 = self-edge
        colidx[rs]  = i;
    }
    if (blockIdx.x == 0 && threadIdx.x == 0) rowstart[N] = EN;
}

// --- Fused MFMA GEMM + fill -------------------------------------------------
__global__ __launch_bounds__(256) void gemm_fill_kernel(const _Float16* __restrict__ Xh,
                                                        const _Float16* __restrict__ WB,
                                                        const float* __restrict__ dinv,
                                                        _Float16* __restrict__ Gh,
                                                        const int* __restrict__ ei,
                                                        int* __restrict__ cursor,
                                                        int* __restrict__ colidx,
                                                        int N, int E, int EN, int gb) {
    if ((int)blockIdx.x >= gb) {
        int e = ((int)blockIdx.x - gb) * 256 + (int)threadIdx.x;
        if (e < E) {
            int d = ei[E + e];
            if (d >= 0 && d < N) {
                int slot = atomicAdd(&cursor[d], 1);
                if (slot >= 0 && slot < EN) {
                    int s = ei[e];
                    colidx[slot] = min(max(s, 0), N - 1);
                }
            }
        }
        return;
    }

    int t = (int)threadIdx.x;
    int wave = t >> 6, lane = t & 63;
    int mbase = blockIdx.x * 64 + wave * 16;
    int arow  = mbase + (lane & 15);
    if (arow >= N) arow = N - 1;             // clamped duplicate reads
    int kgrp  = lane >> 4;                   // 0..3

    f16x8 afrag[4];
#pragma unroll
    for (int kt = 0; kt < 4; ++kt) {
        uint4 u = *(const uint4*)(Xh + (size_t)arow * D + kt * 32 + kgrp * 8);
        afrag[kt] = __builtin_bit_cast(f16x8, u);
    }
    f32x4 acc[8];
#pragma unroll
    for (int nt = 0; nt < 8; ++nt) acc[nt] = (f32x4){0.f, 0.f, 0.f, 0.f};
#pragma unroll
    for (int kt = 0; kt < 4; ++kt) {
#pragma unroll
        for (int nt = 0; nt < 8; ++nt) {
            uint4 u = *(const uint4*)(WB + (((kt * 8 + nt) * 64 + lane) * 8));
            f16x8 bfrag = __builtin_bit_cast(f16x8, u);
            acc[nt] = __builtin_amdgcn_mfma_f32_16x16x32_f16(afrag[kt], bfrag, acc[nt], 0, 0, 0);
        }
    }
    // C/D: col = lane&15, row = kgrp*4 + reg   [m89-verified, dtype-indep]
    int r0 = mbase + kgrp * 4;
#pragma unroll
    for (int r = 0; r < 4; ++r) {
        int row = r0 + r;
        if (row < N) {
            float dv = dinv[row];
#pragma unroll
            for (int nt = 0; nt < 8; ++nt)
                Gh[(size_t)row * D + nt * 16 + (lane & 15)] = (_Float16)(dv * acc[nt][r]);
        }
    }
}

// --- agg1: flat segmented gather-reduce over [rowstart[i0], rowstart[i1]) ---
// Segment of node i = self-edge + in-edges. Flush on uniform boundary cross.
__global__ __launch_bounds__(256) void agg1_kernel(const unsigned* __restrict__ Gh,
                                                   const int* __restrict__ rowstart,
                                                   const int* __restrict__ colidx,
                                                   const float* __restrict__ dinv,
                                                   const float* __restrict__ b1,
                                                   unsigned* __restrict__ Hh,
                                                   int N, int chunk) {
    int gid  = blockIdx.x * 4 + (threadIdx.x >> 6);
    int lane = threadIdx.x & 63;
    int i0 = gid * chunk, i1 = min(i0 + chunk, N);
    if (i0 >= N) return;
    float bx = b1[2 * lane], by = b1[2 * lane + 1];

    int i    = i0;
    int eEnd = rowstart[i + 1];
    int e    = rowstart[i0];
    int eTot = rowstart[i1];
    float2 acc = make_float2(0.f, 0.f);

    while (e + 8 <= eTot) {
        int s[8];
        unsigned u[8];
#pragma unroll
        for (int j = 0; j < 8; ++j) s[j] = colidx[e + j];
#pragma unroll
        for (int j = 0; j < 8; ++j) u[j] = Gh[(size_t)s[j] * (D / 2) + lane];
#pragma unroll
        for (int j = 0; j < 8; ++j) {
            while (e + j >= eEnd) {            // node i complete (uniform)
                float di = dinv[i];
                float hx = fmaxf(fmaf(di, acc.x, bx), 0.f) * di;
                float hy = fmaxf(fmaf(di, acc.y, by), 0.f) * di;
                Hh[(size_t)i * (D / 2) + lane] = f2h(hx, hy);
                acc = make_float2(0.f, 0.f);
                ++i;
                eEnd = rowstart[i + 1];
            }
            float2 v = h2f(u[j]);
            acc.x += v.x;
            acc.y += v.y;
        }
        e += 8;
    }
    while (e < eTot) {
        while (e >= eEnd) {
            float di = dinv[i];
            float hx = fmaxf(fmaf(di, acc.x, bx), 0.f) * di;
            float hy = fmaxf(fmaf(di, acc.y, by), 0.f) * di;
            Hh[(size_t)i * (D / 2) + lane] = f2h(hx, hy);
            acc = make_float2(0.f, 0.f);
            ++i;
            eEnd = rowstart[i + 1];
        }
        float2 v = h2f(Gh[(size_t)colidx[e] * (D / 2) + lane]);
        acc.x += v.x;
        acc.y += v.y;
        ++e;
    }
    for (; i < i1; ++i) {                      // final node(s)
        float di = dinv[i];
        float hx = fmaxf(fmaf(di, acc.x, bx), 0.f) * di;
        float hy = fmaxf(fmaf(di, acc.y, by), 0.f) * di;
        Hh[(size_t)i * (D / 2) + lane] = f2h(hx, hy);
        acc = make_float2(0.f, 0.f);
    }
}

// --- agg2 + pool: same flat stream; per-node result folds into pool accum ---
__global__ __launch_bounds__(256) void agg2_pool_kernel(const unsigned* __restrict__ Hh,
                                                        const int* __restrict__ rowstart,
                                                        const int* __restrict__ colidx,
                                                        const float* __restrict__ dinv,
                                                        const int* __restrict__ batch,
                                                        float* __restrict__ pool,
                                                        int N, int chunk) {
    int gid  = blockIdx.x * 4 + (threadIdx.x >> 6);
    int lane = threadIdx.x & 63;
    int i0 = gid * chunk, i1 = min(i0 + chunk, N);
    if (i0 >= N) return;

    int i    = i0;
    int eEnd = rowstart[i + 1];
    int e    = rowstart[i0];
    int eTot = rowstart[i1];
    float2 acc = make_float2(0.f, 0.f);
    float2 pa  = make_float2(0.f, 0.f);
    int cur = min(max(batch[i0], 0), NGRAPH - 1);

    while (e + 8 <= eTot) {
        int s[8];
        unsigned u[8];
#pragma unroll
        for (int j = 0; j < 8; ++j) s[j] = colidx[e + j];
#pragma unroll
        for (int j = 0; j < 8; ++j) u[j] = Hh[(size_t)s[j] * (D / 2) + lane];
#pragma unroll
        for (int j = 0; j < 8; ++j) {
            while (e + j >= eEnd) {            // node i complete (uniform)
                float di = dinv[i];
                int b = min(max(batch[i], 0), NGRAPH - 1);
                if (b != cur) {
                    atomicAdd(&pool[(size_t)cur * D + 2 * lane], pa.x);
                    atomicAdd(&pool[(size_t)cur * D + 2 * lane + 1], pa.y);
                    pa = make_float2(0.f, 0.f);
                    cur = b;
                }
                pa.x = fmaf(di, acc.x, pa.x);
                pa.y = fmaf(di, acc.y, pa.y);
                acc = make_float2(0.f, 0.f);
                ++i;
                eEnd = rowstart[i + 1];
            }
            float2 v = h2f(u[j]);
            acc.x += v.x;
            acc.y += v.y;
        }
        e += 8;
    }
    while (e < eTot) {
        while (e >= eEnd) {
            float di = dinv[i];
            int b = min(max(batch[i], 0), NGRAPH - 1);
            if (b != cur) {
                atomicAdd(&pool[(size_t)cur * D + 2 * lane], pa.x);
                atomicAdd(&pool[(size_t)cur * D + 2 * lane + 1], pa.y);
                pa = make_float2(0.f, 0.f);
                cur = b;
            }
            pa.x = fmaf(di, acc.x, pa.x);
            pa.y = fmaf(di, acc.y, pa.y);
            acc = make_float2(0.f, 0.f);
            ++i;
            eEnd = rowstart[i + 1];
        }
        float2 v = h2f(Hh[(size_t)colidx[e] * (D / 2) + lane]);
        acc.x += v.x;
        acc.y += v.y;
        ++e;
    }
    for (; i < i1; ++i) {
        float di = dinv[i];
        int b = min(max(batch[i], 0), NGRAPH - 1);
        if (b != cur) {
            atomicAdd(&pool[(size_t)cur * D + 2 * lane], pa.x);
            atomicAdd(&pool[(size_t)cur * D + 2 * lane + 1], pa.y);
            pa = make_float2(0.f, 0.f);
            cur = b;
        }
        pa.x = fmaf(di, acc.x, pa.x);
        pa.y = fmaf(di, acc.y, pa.y);
        acc = make_float2(0.f, 0.f);
    }
    atomicAdd(&pool[(size_t)cur * D + 2 * lane], pa.x);
    atomicAdd(&pool[(size_t)cur * D + 2 * lane + 1], pa.y);
}

// --- Final tiny GEMM: out[g][o] = (pool[g]/cnt_g) . W2[:,o] + b2[o] ---------
__device__ __forceinline__ int lbound(const int* __restrict__ a, int n, int v) {
    int lo = 0, hi = n;
    while (lo < hi) {
        int m = (lo + hi) >> 1;
        if (a[m] < v) lo = m + 1; else hi = m;
    }
    return lo;
}

__global__ void final_gemm_kernel(const float* __restrict__ pool,
                                  const int* __restrict__ batch,
                                  const float* __restrict__ W2,
                                  const float* __restrict__ b2,
                                  float* __restrict__ out, int N) {
    int g = blockIdx.x, o = threadIdx.x;
    int s = lbound(batch, N, g);
    int e = lbound(batch, N, g + 1);
    float inv_cnt = 1.0f / fmaxf((float)(e - s), 1.0f);
    float acc = 0.f;
#pragma unroll 4
    for (int k = 0; k < D; ++k)
        acc = fmaf(pool[g * D + k], W2[k * D + o], acc);
    out[g * D + o] = acc * inv_cnt + b2[o];
}

// ---------------------------------------------------------------------------

extern "C" void kernel_launch(void* const* d_in, const int* in_sizes, int n_in,
                              void* d_out, int out_size, void* d_ws, size_t ws_size,
                              hipStream_t stream) {
    const float* x     = (const float*)d_in[0];
    const int*   ei    = (const int*)  d_in[1];
    const int*   batch = (const int*)  d_in[2];
    const float* W1    = (const float*)d_in[3];
    const float* b1    = (const float*)d_in[4];
    const float* W2    = (const float*)d_in[5];
    const float* b2    = (const float*)d_in[6];
    float* out = (float*)d_out;

    const int N = in_sizes[0] / D;
    const int E = in_sizes[1] / 2;
    const int EN = E + N;                          // edges + self-edges
    const int nblk = (N + SCAN_B - 1) / SCAN_B;    // <=64 for N<=65536

    // workspace carve-up (256B aligned); deg+pool adjacent -> single memset
    char* ws = (char*)d_ws;
    size_t off = 0;
    auto carve = [&](size_t bytes) {
        size_t o = off;
        off = (off + bytes + 255) & ~(size_t)255;
        return o;
    };
    size_t o_deg      = carve((size_t)N * 4);
    size_t o_pool     = carve((size_t)NGRAPH * D * 4);
    size_t zspan      = off;                       // memset [0, zspan)
    size_t o_rowstart = carve((size_t)(N + 1) * 4);
    size_t o_cursor   = carve((size_t)(N + 1) * 4);
    size_t o_dinv     = carve((size_t)N * 4);
    size_t o_colidx   = carve((size_t)EN * 4);
    size_t o_bsum     = carve((size_t)64 * 4);
    size_t o_xh       = carve((size_t)N * D * 2);  // fp16 X
    size_t o_wb       = carve((size_t)D * D * 2);  // fp16 W1 (MFMA B order)
    size_t o_gh       = carve((size_t)N * D * 2);  // fp16 G'
    size_t o_hh       = carve((size_t)N * D * 2);  // fp16 H''
    size_t need = off;

    if (ws_size < need) {
        zero_out_kernel<<<(out_size + 255) / 256, 256, 0, stream>>>(out, out_size);
        return;
    }

    int*       deg      = (int*)      (ws + o_deg);
    float*     pool     = (float*)    (ws + o_pool);
    int*       rowstart = (int*)      (ws + o_rowstart);
    int*       cursor   = (int*)      (ws + o_cursor);
    float*     dinv     = (float*)    (ws + o_dinv);
    int*       colidx   = (int*)      (ws + o_colidx);
    int*       bsum     = (int*)      (ws + o_bsum);
    _Float16*  Xh       = (_Float16*) (ws + o_xh);
    _Float16*  WB       = (_Float16*) (ws + o_wb);
    _Float16*  Gh       = (_Float16*) (ws + o_gh);
    _Float16*  Hh       = (_Float16*) (ws + o_hh);

    hipMemsetAsync(ws, 0, zspan, stream);          // deg + pool in one shot

    int eb = (E + 255) / 256;
    int gb = (N + 63) / 64;
    int cb = (N * (D / 4) + 255) / 256;            // X float4-groups

    conv_count_kernel<<<cb + 8 + eb, 256, 0, stream>>>(x, Xh, W1, WB, ei, deg, N, E, cb);
    block_scan_kernel<<<nblk, SCAN_B, 0, stream>>>(deg, rowstart, bsum, dinv, N);
    finalize_scan_kernel<<<nblk, SCAN_B, 0, stream>>>(bsum, rowstart, cursor, colidx,
                                                      N, nblk, EN);
    gemm_fill_kernel<<<gb + eb, 256, 0, stream>>>(Xh, WB, dinv, Gh, ei, cursor,
                                                  colidx, N, E, EN, gb);

    int groups = AGG_BLOCKS * 4;
    int chunk  = (N + groups - 1) / groups;
    agg1_kernel<<<AGG_BLOCKS, 256, 0, stream>>>((const unsigned*)Gh, rowstart, colidx,
                                                dinv, b1, (unsigned*)Hh, N, chunk);
    agg2_pool_kernel<<<AGG_BLOCKS, 256, 0, stream>>>((const unsigned*)Hh, rowstart, colidx,
                                                     dinv, batch, pool, N, chunk);
    final_gemm_kernel<<<NGRAPH, D, 0, stream>>>(pool, batch, W2, b2, out, N);
}